// Round 1
// baseline (70.890 us; speedup 1.0000x reference)
//
#include <hip/hip_runtime.h>
#include <math.h>

// Problem constants (from reference):
//   B=4096, T=256, V=16, E=10, H=50, O=16
// Key insight: reference uses only h_t[:, -1], which depends solely on
// x[b, T-1] (one of 16 token values). So precompute a V x O table and gather.

#define BB 4096
#define TT 256
#define VV 16
#define EE 10
#define HH 50
#define OO 16

__device__ __forceinline__ float sigmoidf_(float v) {
    return 1.0f / (1.0f + expf(-v));
}

__global__ __launch_bounds__(256) void dclstm_table_gather(
    const int*   __restrict__ x,
    const float* __restrict__ emb,
    const float* __restrict__ w1,
    const float* __restrict__ b1,
    const float* __restrict__ b2,
    const float* __restrict__ w_out,
    const float* __restrict__ b_out,
    float*       __restrict__ out)
{
    __shared__ float ht_s[VV * HH];     // h_t for each token, 16x50
    __shared__ float table[VV * OO];    // final out row per token, 16x16

    const int tid = threadIdx.x;        // 256 threads
    const int v  = tid >> 4;            // token 0..15
    const int lo = tid & 15;            // sub-index 0..15

    // ---- Phase 1: thread (v, lo) computes LSTM-cell units j = lo, lo+16, ...
    float xe[EE];
    #pragma unroll
    for (int e = 0; e < EE; ++e) xe[e] = emb[v * EE + e];

    for (int j = lo; j < HH; j += 16) {
        float pi = b1[j]            + b2[j];             // input gate preact
        float po = b1[2 * HH + j]   + b2[2 * HH + j];    // output gate preact
        float pg = b1[3 * HH + j]   + b2[3 * HH + j];    // g preact
        #pragma unroll
        for (int e = 0; e < EE; ++e) {
            const float xv = xe[e];
            pi = fmaf(xv, w1[j * EE + e],            pi);
            po = fmaf(xv, w1[(2 * HH + j) * EE + e], po);
            pg = fmaf(xv, w1[(3 * HH + j) * EE + e], pg);
        }
        const float i_t = sigmoidf_(pi);
        const float o_t = sigmoidf_(po);
        const float g   = tanhf(pg);
        const float c_t = i_t * g;
        ht_s[v * HH + j] = o_t * tanhf(c_t);
    }
    __syncthreads();

    // ---- Phase 2: thread (v, o) computes table[v][o] = w_out[o] . h[v] + b_out[o]
    {
        const int o = lo;
        float acc = b_out[o];
        #pragma unroll 10
        for (int j = 0; j < HH; ++j)
            acc = fmaf(w_out[o * HH + j], ht_s[v * HH + j], acc);
        table[v * OO + o] = acc;
    }
    __syncthreads();

    // ---- Phase 3: gather. Block handles 16 consecutive batch rows.
    const int row = blockIdx.x * 16 + (tid >> 4);
    if (row < BB) {
        const int tok = x[row * TT + (TT - 1)];
        out[row * OO + lo] = table[tok * OO + lo];
    }
}

extern "C" void kernel_launch(void* const* d_in, const int* in_sizes, int n_in,
                              void* d_out, int out_size, void* d_ws, size_t ws_size,
                              hipStream_t stream) {
    const int*   x     = (const int*)  d_in[0];
    const float* emb   = (const float*)d_in[1];
    const float* w1    = (const float*)d_in[2];
    const float* b1    = (const float*)d_in[3];
    // d_in[4] = w2 — unused by the reference math (only b2 is added)
    const float* b2    = (const float*)d_in[5];
    const float* w_out = (const float*)d_in[6];
    const float* b_out = (const float*)d_in[7];
    float* out = (float*)d_out;

    dclstm_table_gather<<<dim3(BB / 16), dim3(256), 0, stream>>>(
        x, emb, w1, b1, b2, w_out, b_out, out);
}

// Round 2
// 70.750 us; speedup vs baseline: 1.0020x; 1.0020x over previous
//
#include <hip/hip_runtime.h>
#include <math.h>

// Problem constants (from reference):
//   B=4096, T=256, V=16, E=10, H=50, O=16
// Key insight: reference uses only h_t[:, -1], which depends solely on
// x[b, T-1] (one of 16 token values). So precompute a V x O table and gather.
// w2 never enters the math (only b2 is added).

#define BB 4096
#define TT 256
#define VV 16
#define EE 10
#define HH 50
#define OO 16

__device__ __forceinline__ float sigmoidf_(float v) {
    return 1.0f / (1.0f + expf(-v));
}

__global__ __launch_bounds__(256) void dclstm_table_gather(
    const int*   __restrict__ x,
    const float* __restrict__ emb,
    const float* __restrict__ w1,
    const float* __restrict__ b1,
    const float* __restrict__ b2,
    const float* __restrict__ w_out,
    const float* __restrict__ b_out,
    float*       __restrict__ out)
{
    __shared__ float ht_s[VV * HH];     // h_t for each token, 16x50
    __shared__ float table[VV * OO];    // final out row per token, 16x16

    const int tid = threadIdx.x;        // 256 threads
    const int v  = tid >> 4;            // token 0..15 (also row-within-block)
    const int lo = tid & 15;            // sub-index 0..15

    // ---- Issue the gather load FIRST: independent of the table, and the
    // barriers below would otherwise fence it to the end (~900-cycle HBM
    // latency exposed). grid is exactly BB/16 blocks -> no bounds check.
    const int row = blockIdx.x * 16 + v;
    const int tok = x[row * TT + (TT - 1)];   // in flight during phase 1/2

    // ---- Phase 1: thread (v, lo) computes LSTM-cell units j = lo, lo+16, ...
    float xe[EE];
    #pragma unroll
    for (int e = 0; e < EE; ++e) xe[e] = emb[v * EE + e];

    #pragma unroll
    for (int j = lo; j < HH; j += 16) {
        float pi = b1[j]            + b2[j];             // input gate preact
        float po = b1[2 * HH + j]   + b2[2 * HH + j];    // output gate preact
        float pg = b1[3 * HH + j]   + b2[3 * HH + j];    // g preact
        #pragma unroll
        for (int e = 0; e < EE; ++e) {
            const float xv = xe[e];
            pi = fmaf(xv, w1[j * EE + e],            pi);
            po = fmaf(xv, w1[(2 * HH + j) * EE + e], po);
            pg = fmaf(xv, w1[(3 * HH + j) * EE + e], pg);
        }
        const float i_t = sigmoidf_(pi);
        const float o_t = sigmoidf_(po);
        const float g   = tanhf(pg);
        const float c_t = i_t * g;
        ht_s[v * HH + j] = o_t * tanhf(c_t);
    }
    __syncthreads();

    // ---- Phase 2: thread (v, o) computes table[v][o] = w_out[o] . h[v] + b_out[o]
    {
        const int o = lo;
        float acc = b_out[o];
        #pragma unroll 10
        for (int j = 0; j < HH; ++j)
            acc = fmaf(w_out[o * HH + j], ht_s[v * HH + j], acc);
        table[v * OO + o] = acc;
    }
    __syncthreads();

    // ---- Phase 3: gather through the table; coalesced 1 KB store per block.
    out[row * OO + lo] = table[tok * OO + lo];
}

extern "C" void kernel_launch(void* const* d_in, const int* in_sizes, int n_in,
                              void* d_out, int out_size, void* d_ws, size_t ws_size,
                              hipStream_t stream) {
    const int*   x     = (const int*)  d_in[0];
    const float* emb   = (const float*)d_in[1];
    const float* w1    = (const float*)d_in[2];
    const float* b1    = (const float*)d_in[3];
    // d_in[4] = w2 — unused by the reference math (only b2 is added)
    const float* b2    = (const float*)d_in[5];
    const float* w_out = (const float*)d_in[6];
    const float* b_out = (const float*)d_in[7];
    float* out = (float*)d_out;

    dclstm_table_gather<<<dim3(BB / 16), dim3(256), 0, stream>>>(
        x, emb, w1, b1, b2, w_out, b_out, out);
}